// Round 1
// baseline (41.921 us; speedup 1.0000x reference)
//
#include <hip/hip_runtime.h>
#include <math.h>

#define HALF 256
#define BTOT 512
#define DIM 256

constexpr float PD_EPS   = 1e-6f;
constexpr float NORM_EPS = 1e-12f;
constexpr float INV_TEMP = 2.0f;   // 1 / 0.5
constexpr float MARGIN   = 2.5f;

// ---------------------------------------------------------------------------
// Kernel A: L2-normalize each of the 512 rows (256 from emb_i, 256 from emb_j)
// into reps[512][256] in workspace. One block (256 thr) per row.
// ---------------------------------------------------------------------------
__global__ void __launch_bounds__(256) normalize_rows(
    const float* __restrict__ emb_i,
    const float* __restrict__ emb_j,
    float* __restrict__ reps)
{
    const int row = blockIdx.x;
    const int t   = threadIdx.x;
    const float* src = (row < HALF) ? (emb_i + row * DIM)
                                    : (emb_j + (row - HALF) * DIM);
    float x = src[t];

    // sum of squares: wave64 shuffle reduce, then cross-wave via LDS
    float s = x * x;
    #pragma unroll
    for (int off = 32; off >= 1; off >>= 1)
        s += __shfl_down(s, off, 64);

    __shared__ float wsum[4];
    const int lane = t & 63;
    const int wave = t >> 6;
    if (lane == 0) wsum[wave] = s;
    __syncthreads();
    const float tot = wsum[0] + wsum[1] + wsum[2] + wsum[3];

    const float n   = sqrtf(tot);
    const float inv = 1.0f / fmaxf(n, NORM_EPS);
    reps[row * DIM + t] = x * inv;
}

// ---------------------------------------------------------------------------
// Kernel B: one block (512 thr) per row a. Thread b computes the pair term
// for (a, b). Row a staged in LDS; row b read via float4 (L2-resident).
// Block-reduce the 512 terms -> partial[a].
// ---------------------------------------------------------------------------
__global__ void __launch_bounds__(512) pair_loss(
    const float* __restrict__ reps,
    const int*   __restrict__ y,
    float*       __restrict__ partial)
{
    const int a = blockIdx.x;
    const int b = threadIdx.x;

    __shared__ float ra[DIM];
    if (b < DIM) ra[b] = reps[a * DIM + b];
    __syncthreads();

    const int ya = y[a];
    const int yb = y[b];

    const float4* rb4 = (const float4*)(reps + b * DIM);
    const float4* ra4 = (const float4*)ra;

    float acc = 0.0f;
    #pragma unroll 8
    for (int q = 0; q < DIM / 4; ++q) {
        const float4 v = rb4[q];       // global (L2 hit)
        const float4 u = ra4[q];       // LDS broadcast (uniform addr)
        float d0 = u.x - v.x + PD_EPS;
        float d1 = u.y - v.y + PD_EPS;
        float d2 = u.z - v.z + PD_EPS;
        float d3 = u.w - v.w + PD_EPS;
        acc += d0 * d0 + d1 * d1 + d2 * d2 + d3 * d3;
    }

    const float dist = sqrtf(acc);
    const float d    = dist * INV_TEMP;

    float term;
    if (a == b) {
        term = 0.0f;
    } else if (ya == yb) {
        term = d * d;                          // NUM = 1
    } else {
        const float f = fmaxf(MARGIN - d, 0.0f);
        term = f * f;
    }

    // block reduction over 512 threads (8 waves)
    const int lane = b & 63;
    const int wave = b >> 6;
    float v = term;
    #pragma unroll
    for (int off = 32; off >= 1; off >>= 1)
        v += __shfl_down(v, off, 64);

    __shared__ float wsum[8];
    if (lane == 0) wsum[wave] = v;
    __syncthreads();
    if (wave == 0) {
        float x = (lane < 8) ? wsum[lane] : 0.0f;
        #pragma unroll
        for (int off = 4; off >= 1; off >>= 1)
            x += __shfl_down(x, off, 64);
        if (lane == 0) partial[a] = x;
    }
}

// ---------------------------------------------------------------------------
// Kernel C: reduce the 512 per-row partials -> loss = sum / (2*B)
// ---------------------------------------------------------------------------
__global__ void __launch_bounds__(512) final_reduce(
    const float* __restrict__ partial,
    float*       __restrict__ out)
{
    const int t = threadIdx.x;
    float v = partial[t];

    const int lane = t & 63;
    const int wave = t >> 6;
    #pragma unroll
    for (int off = 32; off >= 1; off >>= 1)
        v += __shfl_down(v, off, 64);

    __shared__ float wsum[8];
    if (lane == 0) wsum[wave] = v;
    __syncthreads();
    if (wave == 0) {
        float x = (lane < 8) ? wsum[lane] : 0.0f;
        #pragma unroll
        for (int off = 4; off >= 1; off >>= 1)
            x += __shfl_down(x, off, 64);
        if (lane == 0) out[0] = x * (1.0f / (2.0f * (float)BTOT));
    }
}

// ---------------------------------------------------------------------------
extern "C" void kernel_launch(void* const* d_in, const int* in_sizes, int n_in,
                              void* d_out, int out_size, void* d_ws, size_t ws_size,
                              hipStream_t stream)
{
    const float* emb_i = (const float*)d_in[0];
    const float* emb_j = (const float*)d_in[1];
    const int*   y     = (const int*)d_in[2];
    float*       out   = (float*)d_out;

    float* reps    = (float*)d_ws;                 // 512*256 floats = 512 KB
    float* partial = reps + BTOT * DIM;            // 512 floats

    normalize_rows<<<BTOT, 256, 0, stream>>>(emb_i, emb_j, reps);
    pair_loss<<<BTOT, 512, 0, stream>>>(reps, y, partial);
    final_reduce<<<1, 512, 0, stream>>>(partial, out);
}

// Round 2
// 24.934 us; speedup vs baseline: 1.6813x; 1.6813x over previous
//
#include <hip/hip_runtime.h>
#include <math.h>

#define HALF 256
#define BTOT 512
#define DIM  256
#define TILE 64
#define NSIDE 8          // 512 / 64
#define LSTR 260         // LDS row stride (floats): 16B-aligned, spreads banks

constexpr float PD_EPS   = 1e-6f;
constexpr float NORM_EPS = 1e-12f;
constexpr float MARGIN   = 2.5f;

// ---------------------------------------------------------------------------
// One block per 64x64 tile of the 512x512 pair matrix.
// Stages raw rows, normalizes in-block, computes pair terms via dot products:
//   ||a - b + eps||^2 = 2 - 2*dot(a,b) + 2*eps*(sum_a - sum_b) + D*eps^2
// (a, b unit-normalized). Positives need no sqrt at all.
// ---------------------------------------------------------------------------
__global__ void __launch_bounds__(256) tile_loss(
    const float* __restrict__ emb_i,
    const float* __restrict__ emb_j,
    const int*   __restrict__ y,
    float*       __restrict__ partial)
{
    const int bi = blockIdx.x;          // tile row block 0..7
    const int bj = blockIdx.y;          // tile col block 0..7
    const int t  = threadIdx.x;         // 0..255

    __shared__ float A [TILE][LSTR];
    __shared__ float Bs[TILE][LSTR];
    __shared__ float invnA[TILE], snA[TILE];
    __shared__ float invnB[TILE], snB[TILE];
    __shared__ int   yA[TILE], yB[TILE];
    __shared__ float wsum[4];

    const int rowA0 = bi * TILE;
    const int rowB0 = bj * TILE;
    // 64 | 256, so each 64-row panel lies entirely in emb_i or emb_j
    const float* srcA = (rowA0 < HALF) ? (emb_i + rowA0 * DIM)
                                       : (emb_j + (rowA0 - HALF) * DIM);
    const float* srcB = (rowB0 < HALF) ? (emb_i + rowB0 * DIM)
                                       : (emb_j + (rowB0 - HALF) * DIM);

    // ---- stage both 64x256 panels, fully coalesced float4 ----
    const float4* gA = (const float4*)srcA;   // 4096 float4, contiguous
    const float4* gB = (const float4*)srcB;
    #pragma unroll
    for (int k = 0; k < 16; ++k) {
        const int idx = k * 256 + t;          // float4 index 0..4095
        const int r = idx >> 6;               // 64 float4 per row
        const int c = idx & 63;
        float4 va = gA[idx];
        float4 vb = gB[idx];
        *(float4*)&A [r][c * 4] = va;
        *(float4*)&Bs[r][c * 4] = vb;
    }
    if (t < TILE)          yA[t]        = y[rowA0 + t];
    else if (t < 2 * TILE) yB[t - TILE] = y[rowB0 + (t - TILE)];
    __syncthreads();

    // ---- per-row norms + sums: 2 threads per row (128 rows) ----
    {
        const int r  = t >> 1;                // 0..127
        const int hh = t & 1;
        const float* lrow = (r < TILE) ? &A[r][0] : &Bs[r - TILE][0];
        const float4* lp  = (const float4*)(lrow + hh * 128);
        float ss = 0.0f, sm = 0.0f;
        #pragma unroll
        for (int q = 0; q < 32; ++q) {
            float4 v = lp[q];
            ss += v.x * v.x + v.y * v.y + v.z * v.z + v.w * v.w;
            sm += v.x + v.y + v.z + v.w;
        }
        ss += __shfl_xor(ss, 1, 64);
        sm += __shfl_xor(sm, 1, 64);
        if (hh == 0) {
            const float inv = 1.0f / fmaxf(sqrtf(ss), NORM_EPS);
            if (r < TILE) { invnA[r] = inv;        snA[r] = sm * inv; }
            else          { invnB[r - TILE] = inv; snB[r - TILE] = sm * inv; }
        }
    }
    __syncthreads();

    // ---- 16 pairs per thread: i in i0+{0,16,32,48}, j in j0+{0,16,32,48} ----
    const int i0 = t >> 4;    // 0..15
    const int j0 = t & 15;    // 0..15

    float acc[4][4];
    #pragma unroll
    for (int ii = 0; ii < 4; ++ii)
        #pragma unroll
        for (int jj = 0; jj < 4; ++jj) acc[ii][jj] = 0.0f;

    #pragma unroll 4
    for (int q = 0; q < 64; ++q) {
        float4 av[4], bv[4];
        #pragma unroll
        for (int ii = 0; ii < 4; ++ii)
            av[ii] = *(const float4*)&A[i0 + 16 * ii][q * 4];
        #pragma unroll
        for (int jj = 0; jj < 4; ++jj)
            bv[jj] = *(const float4*)&Bs[j0 + 16 * jj][q * 4];
        #pragma unroll
        for (int ii = 0; ii < 4; ++ii)
            #pragma unroll
            for (int jj = 0; jj < 4; ++jj)
                acc[ii][jj] += av[ii].x * bv[jj].x + av[ii].y * bv[jj].y
                             + av[ii].z * bv[jj].z + av[ii].w * bv[jj].w;
    }

    // ---- per-pair loss terms ----
    float tsum = 0.0f;
    #pragma unroll
    for (int ii = 0; ii < 4; ++ii) {
        const int   il = i0 + 16 * ii;
        const int   gi = rowA0 + il;
        const float ia = invnA[il];
        const float sa = snA[il];
        const int   la = yA[il];
        #pragma unroll
        for (int jj = 0; jj < 4; ++jj) {
            const int jl = j0 + 16 * jj;
            const int gj = rowB0 + jl;
            const float dotn = acc[ii][jj] * ia * invnB[jl];
            float dist2 = 2.0f - 2.0f * dotn
                        + 2.0f * PD_EPS * (sa - snB[jl])
                        + (float)DIM * PD_EPS * PD_EPS;
            dist2 = fmaxf(dist2, 0.0f);
            float term = 0.0f;
            if (gi != gj) {
                if (la == yB[jl]) {
                    term = 4.0f * dist2;                    // (2*dist)^2, no sqrt
                } else {
                    const float d = 2.0f * sqrtf(dist2);
                    const float f = fmaxf(MARGIN - d, 0.0f);
                    term = f * f;
                }
            }
            tsum += term;
        }
    }

    // ---- block reduce 256 -> 1 ----
    const int lane = t & 63;
    const int wave = t >> 6;
    #pragma unroll
    for (int off = 32; off >= 1; off >>= 1)
        tsum += __shfl_down(tsum, off, 64);
    if (lane == 0) wsum[wave] = tsum;
    __syncthreads();
    if (t == 0)
        partial[bi * NSIDE + bj] = wsum[0] + wsum[1] + wsum[2] + wsum[3];
}

// ---------------------------------------------------------------------------
// Reduce the 64 tile partials -> loss = sum / (2*B)
// ---------------------------------------------------------------------------
__global__ void __launch_bounds__(64) final_reduce(
    const float* __restrict__ partial,
    float*       __restrict__ out)
{
    const int t = threadIdx.x;
    float v = partial[t];
    #pragma unroll
    for (int off = 32; off >= 1; off >>= 1)
        v += __shfl_down(v, off, 64);
    if (t == 0) out[0] = v * (1.0f / (2.0f * (float)BTOT));
}

// ---------------------------------------------------------------------------
extern "C" void kernel_launch(void* const* d_in, const int* in_sizes, int n_in,
                              void* d_out, int out_size, void* d_ws, size_t ws_size,
                              hipStream_t stream)
{
    const float* emb_i = (const float*)d_in[0];
    const float* emb_j = (const float*)d_in[1];
    const int*   y     = (const int*)d_in[2];
    float*       out   = (float*)d_out;

    float* partial = (float*)d_ws;   // 64 floats

    tile_loss<<<dim3(NSIDE, NSIDE), 256, 0, stream>>>(emb_i, emb_j, y, partial);
    final_reduce<<<1, 64, 0, stream>>>(partial, out);
}